// Round 9
// baseline (2462.109 us; speedup 1.0000x reference)
//
#include <hip/hip_runtime.h>
#include <cstdint>
#include <cstddef>

static constexpr int TT = 1024;   // time steps
static constexpr int BB = 32;     // batch
static constexpr int CC = 256;    // channels (= 2H)
static constexpr int HH = 128;    // hidden per direction
static constexpr int GG = 512;    // 4H gates
static constexpr int MM = TT * BB;

__device__ __forceinline__ float fsig(float x) { return 1.f / (1.f + __expf(-x)); }
__device__ __forceinline__ float ftanh(float x) {
  float e = __expf(2.f * x);
  return 1.f - 2.f / (e + 1.f);
}

// Workgroup barrier with LDS-only (lgkmcnt) drain: gx prefetch loads are
// thread-private and hout stores are never re-read, so vmcnt/expcnt drain
// (__syncthreads semantics) would only expose HBM latency on the critical path.
__device__ __forceinline__ void barrier_lds_only() {
  asm volatile("s_waitcnt lgkmcnt(0)" ::: "memory");
  __builtin_amdgcn_s_barrier();
  asm volatile("" ::: "memory");
}

// ---------------- x[B][C][T] -> xs[T][B][C] ----------------
__global__ __launch_bounds__(256) void k_transpose_in(const float* __restrict__ x,
                                                      float* __restrict__ xs) {
  __shared__ float tile[32][33];
  const int t0 = blockIdx.x * 32, c0 = blockIdx.y * 32, b = blockIdx.z;
  const int tx = threadIdx.x, ty = threadIdx.y;
#pragma unroll
  for (int i = 0; i < 4; i++) {
    const int cc = ty + i * 8;
    tile[cc][tx] = x[((size_t)b * CC + (c0 + cc)) * TT + t0 + tx];
  }
  __syncthreads();
#pragma unroll
  for (int i = 0; i < 4; i++) {
    const int tt = ty + i * 8;
    xs[((size_t)(t0 + tt) * BB + b) * CC + c0 + tx] = tile[tx][tt];
  }
}

// ---------------- h2[T][B][C] -> out[B][C][T] ----------------
__global__ __launch_bounds__(256) void k_transpose_out(const float* __restrict__ h2,
                                                       float* __restrict__ out) {
  __shared__ float tile[32][33];
  const int t0 = blockIdx.x * 32, c0 = blockIdx.y * 32, b = blockIdx.z;
  const int tx = threadIdx.x, ty = threadIdx.y;
#pragma unroll
  for (int i = 0; i < 4; i++) {
    const int tt = ty + i * 8;
    tile[tt][tx] = h2[((size_t)(t0 + tt) * BB + b) * CC + c0 + tx];
  }
  __syncthreads();
#pragma unroll
  for (int i = 0; i < 4; i++) {
    const int cc = ty + i * 8;
    out[((size_t)b * CC + (c0 + cc)) * TT + t0 + tx] = tile[tx][cc];
  }
}

// ---------------- gx[d][m][g] = X[m][:]·W[d][g][:] + bih[d][g]+bhh[d][g] ----------------
__global__ __launch_bounds__(256) void k_gemm_ih(const float* __restrict__ X,
                                                 const float* __restrict__ W,
                                                 const float* __restrict__ bih,
                                                 const float* __restrict__ bhh,
                                                 float* __restrict__ gx, int M) {
  const int d = blockIdx.z;
  const int row0 = blockIdx.y * 128;
  const int col0 = blockIdx.x * 64;
  const float* Wd = W + (size_t)d * GG * CC;
  __shared__ float As[16][132];  // [k][m], padded
  __shared__ float Ws[16][68];   // [k][n]
  const int tid = threadIdx.x;
  const int tm = tid >> 4;        // 0..15 -> 8 rows each
  const int tn = tid & 15;        // 0..15 -> 4 cols each
  const int lr = tid >> 2;        // 0..63
  const int lk = (tid & 3) * 4;   // 0,4,8,12

  float acc[8][4] = {};
  for (int k0 = 0; k0 < CC; k0 += 16) {
    const float4 a0 = *(const float4*)&X[(size_t)(row0 + lr) * CC + k0 + lk];
    const float4 a1 = *(const float4*)&X[(size_t)(row0 + 64 + lr) * CC + k0 + lk];
    const float4 wv = *(const float4*)&Wd[(size_t)(col0 + lr) * CC + k0 + lk];
    __syncthreads();  // protect LDS from previous iteration's readers
    As[lk + 0][lr] = a0.x; As[lk + 1][lr] = a0.y; As[lk + 2][lr] = a0.z; As[lk + 3][lr] = a0.w;
    As[lk + 0][64 + lr] = a1.x; As[lk + 1][64 + lr] = a1.y; As[lk + 2][64 + lr] = a1.z; As[lk + 3][64 + lr] = a1.w;
    Ws[lk + 0][lr] = wv.x; Ws[lk + 1][lr] = wv.y; Ws[lk + 2][lr] = wv.z; Ws[lk + 3][lr] = wv.w;
    __syncthreads();
#pragma unroll
    for (int kk = 0; kk < 16; kk++) {
      const float4 av0 = *(const float4*)&As[kk][tm * 8];
      const float4 av1 = *(const float4*)&As[kk][tm * 8 + 4];
      const float4 bv = *(const float4*)&Ws[kk][tn * 4];
      const float a[8] = {av0.x, av0.y, av0.z, av0.w, av1.x, av1.y, av1.z, av1.w};
      const float bb4[4] = {bv.x, bv.y, bv.z, bv.w};
#pragma unroll
      for (int i = 0; i < 8; i++)
#pragma unroll
        for (int j = 0; j < 4; j++) acc[i][j] = fmaf(a[i], bb4[j], acc[i][j]);
    }
  }
  float bias[4];
#pragma unroll
  for (int j = 0; j < 4; j++) {
    const int col = col0 + tn * 4 + j;
    bias[j] = bih[d * GG + col] + bhh[d * GG + col];
  }
#pragma unroll
  for (int i = 0; i < 8; i++) {
    const int row = row0 + tm * 8 + i;
    float4 o;
    o.x = acc[i][0] + bias[0];
    o.y = acc[i][1] + bias[1];
    o.z = acc[i][2] + bias[2];
    o.w = acc[i][3] + bias[3];
    *(float4*)&gx[((size_t)d * M + row) * GG + col0 + tn * 4] = o;
  }
}

// ---------------- persistent recurrence: one WG per (d,b) ----------------
// Plan D: thread r (0..511) owns the FULL K=128 dot for gate row r, adds its own
// coalesced gx[r], and applies its own sigmoid/tanh (transcendentals spread over
// all 8 waves; branch is wave-uniform since r>>7 is constant per wave).
// This removes the partial-sum LDS round-trip, the readlanes, and the 2-wave act
// concentration that together (with the fixed 512-cyc fp32 dot issue) formed the
// ~1900 cyc/step invariant of R2-R8.
// Per step: dot = 32 uniform b128 h-reads + 128 FMA (4 chains); act write to
// pad-5 LDS (2-way alias only = free); barrier; j-threads (waves 0-1) do the
// 4-read c-update + 1 tanh; barrier.
__global__ __launch_bounds__(512, 1) void k_lstm_rec(const float* __restrict__ gx,
                                                     const float* __restrict__ Whh,
                                                     float* __restrict__ hout) {
  const int b = blockIdx.x & 31;
  const int d = blockIdx.x >> 5;
  const int r = threadIdx.x;    // gate row 0..511
  const int gi = r >> 7;        // gate 0..3 (i,f,g,o) — wave-uniform
  const int j = r & 127;        // hidden index
  __shared__ __align__(16) float h_s[HH];
  __shared__ float act_s[HH * 5];   // [j][gi], stride 5 words -> conflict-free

  // W_hh row r resident in registers (allocator may choose AGPR; plain-C fma
  // reads it at full rate — R5/R6 showed forcing "v" only adds copies)
  float4 wv[32];
  {
    const float4* wrow = (const float4*)(Whh + ((size_t)d * GG + r) * HH);
#pragma unroll
    for (int k = 0; k < 32; k++) wv[k] = wrow[k];
  }
#pragma unroll
  for (int k = 0; k < 32; k++)
    asm volatile("" : "+v"(wv[k].x), "+v"(wv[k].y), "+v"(wv[k].z), "+v"(wv[k].w));

  if (r < HH) h_s[r] = 0.f;
  float c = 0.f;

  const float* gxb = gx + ((size_t)d * TT * BB + b) * (size_t)GG + r;
  const size_t stride = (size_t)BB * GG;
  int t = d ? (TT - 1) : 0;
  const int tdir = d ? -1 : 1;
  float gxc = gxb[(size_t)t * stride];
  const bool is_g = (gi == 2);
  __syncthreads();  // pre-loop: full drain fine

  for (int s = 0; s < TT; s++) {
    // prefetch next step's gx (1 coalesced load / thread); compiler places the
    // vmcnt wait at the gxc=gxn copy (loop end) -> ~full step of slack
    float gxn = 0.f;
    if (s + 1 < TT) gxn = gxb[(size_t)(t + tdir) * stride];

    // full-K dot: 32 uniform b128 reads (broadcast), 128 FMA in 4 chains
    const float4* hq = (const float4*)h_s;
    float a0 = 0.f, a1 = 0.f, a2 = 0.f, a3 = 0.f;
#pragma unroll
    for (int k = 0; k < 32; k++) {
      const float4 hv = hq[k];
      a0 = fmaf(wv[k].x, hv.x, a0);
      a1 = fmaf(wv[k].y, hv.y, a1);
      a2 = fmaf(wv[k].z, hv.z, a2);
      a3 = fmaf(wv[k].w, hv.w, a3);
    }
    const float pre = ((a0 + a1) + (a2 + a3)) + gxc;
    act_s[j * 5 + gi] = is_g ? ftanh(pre) : fsig(pre);  // own transcendental
    barrier_lds_only();  // act_s visible

    if (r < HH) {  // waves 0-1: c/h update for hidden index r
      const float i_g = act_s[r * 5 + 0];
      const float f_g = act_s[r * 5 + 1];
      const float g_g = act_s[r * 5 + 2];
      const float o_g = act_s[r * 5 + 3];
      c = f_g * c + i_g * g_g;
      const float h = o_g * ftanh(c);
      h_s[r] = h;
      hout[((size_t)t * BB + b) * CC + d * HH + r] = h;
    }
    barrier_lds_only();  // h_s visible for next dot; act_s safe to overwrite
    gxc = gxn;
    t += tdir;
  }
}

extern "C" void kernel_launch(void* const* d_in, const int* in_sizes, int n_in,
                              void* d_out, int out_size, void* d_ws, size_t ws_size,
                              hipStream_t stream) {
  const float* x    = (const float*)d_in[0];
  const float* W_ih = (const float*)d_in[1];  // [2][2][512][256]
  const float* W_hh = (const float*)d_in[2];  // [2][2][512][128]
  const float* b_ih = (const float*)d_in[3];  // [2][2][512]
  const float* b_hh = (const float*)d_in[4];
  float* out = (float*)d_out;

  if (ws_size < (size_t)160 * 1024 * 1024) return;  // need xs(32MiB)+gx(128MiB)

  char* ws = (char*)d_ws;
  float* xs = (float*)ws;                                   // [T][B][C] 32 MiB
  float* gxbuf = (float*)(ws + (size_t)32 * 1024 * 1024);   // [D][M][512] 128 MiB
  float* h1 = out;  // layer-0 hidden staged in d_out (dead before final transpose)
  float* h2 = xs;   // layer-1 hidden reuses xs region (xs dead after layer-0 GEMM)

  const dim3 tb(32, 8);
  const dim3 tg(TT / 32, CC / 32, BB);

  k_transpose_in<<<tg, tb, 0, stream>>>(x, xs);
  k_gemm_ih<<<dim3(GG / 64, MM / 128, 2), 256, 0, stream>>>(xs, W_ih, b_ih, b_hh, gxbuf, MM);
  k_lstm_rec<<<64, 512, 0, stream>>>(gxbuf, W_hh, h1);
  k_gemm_ih<<<dim3(GG / 64, MM / 128, 2), 256, 0, stream>>>(h1, W_ih + 2 * GG * CC,
                                                            b_ih + 2 * GG, b_hh + 2 * GG, gxbuf, MM);
  k_lstm_rec<<<64, 512, 0, stream>>>(gxbuf, W_hh + 2 * GG * HH, h2);
  k_transpose_out<<<tg, tb, 0, stream>>>(h2, out);
}

// Round 10
// 1818.569 us; speedup vs baseline: 1.3539x; 1.3539x over previous
//
#include <hip/hip_runtime.h>
#include <cstdint>
#include <cstddef>

static constexpr int TT = 1024;   // time steps
static constexpr int BB = 32;     // batch
static constexpr int CC = 256;    // channels (= 2H)
static constexpr int HH = 128;    // hidden per direction
static constexpr int GG = 512;    // 4H gates
static constexpr int MM = TT * BB;

typedef float f32x2 __attribute__((ext_vector_type(2)));
typedef float f32x4v __attribute__((ext_vector_type(4)));
typedef short bf16x8 __attribute__((ext_vector_type(8)));

__device__ __forceinline__ float fsig(float x) { return 1.f / (1.f + __expf(-x)); }
__device__ __forceinline__ float ftanh(float x) {
  float e = __expf(2.f * x);
  return 1.f - 2.f / (e + 1.f);
}
__device__ __forceinline__ ushort bf16_rn(float x) {
  union { float f; uint u; } v; v.f = x;
  const uint r = v.u + 0x7fffu + ((v.u >> 16) & 1u);
  return (ushort)(r >> 16);
}
__device__ __forceinline__ float bf16_to_f(ushort h) {
  union { uint u; float f; } v; v.u = ((uint)h) << 16;
  return v.f;
}
__device__ __forceinline__ uint pack2(ushort a, ushort b) { return (uint)a | ((uint)b << 16); }

// ---------------- x[B][C][T] -> Xhi/Xlo[T*B][C] (bf16 hi/lo split) ----------------
__global__ __launch_bounds__(256) void k_transpose_cvt_in(const float* __restrict__ x,
                                                          ushort* __restrict__ xhi,
                                                          ushort* __restrict__ xlo) {
  __shared__ float tile[32][33];
  const int t0 = blockIdx.x * 32, c0 = blockIdx.y * 32, b = blockIdx.z;
  const int tx = threadIdx.x, ty = threadIdx.y;
#pragma unroll
  for (int i = 0; i < 4; i++) {
    const int cc = ty + i * 8;
    tile[cc][tx] = x[((size_t)b * CC + (c0 + cc)) * TT + t0 + tx];
  }
  __syncthreads();
#pragma unroll
  for (int i = 0; i < 4; i++) {
    const int tt = ty + i * 8;
    const float v = tile[tx][tt];
    const ushort hi = bf16_rn(v);
    const size_t idx = ((size_t)(t0 + tt) * BB + b) * CC + c0 + tx;
    xhi[idx] = hi;
    xlo[idx] = bf16_rn(v - bf16_to_f(hi));
  }
}

// ---------------- h2[T][B][C] -> out[B][C][T] ----------------
__global__ __launch_bounds__(256) void k_transpose_out(const float* __restrict__ h2,
                                                       float* __restrict__ out) {
  __shared__ float tile[32][33];
  const int t0 = blockIdx.x * 32, c0 = blockIdx.y * 32, b = blockIdx.z;
  const int tx = threadIdx.x, ty = threadIdx.y;
#pragma unroll
  for (int i = 0; i < 4; i++) {
    const int tt = ty + i * 8;
    tile[tt][tx] = h2[((size_t)(t0 + tt) * BB + b) * CC + c0 + tx];
  }
  __syncthreads();
#pragma unroll
  for (int i = 0; i < 4; i++) {
    const int cc = ty + i * 8;
    out[((size_t)b * CC + (c0 + cc)) * TT + t0 + tx] = tile[tx][cc];
  }
}

// ---------------- MFMA GEMM: gx[d][m][g] = A[m][:]·W[d][g][:] + bias ----------------
// A pre-split bf16 hi/lo [M][256]; W fp32 converted to LDS bf16 hi/lo in-kernel.
// 3-product split (hh + hl + lh) ~ fp32 accuracy. Tile 128m x 64g, BK=64,
// 4 waves (each 64m x 32g = 4x2 16x16 tiles). LDS XOR-swizzled (16B blocks).
__global__ __launch_bounds__(256) void k_gemm_mfma(const ushort* __restrict__ Ahi,
                                                   const ushort* __restrict__ Alo,
                                                   const float* __restrict__ W,
                                                   const float* __restrict__ bih,
                                                   const float* __restrict__ bhh,
                                                   float* __restrict__ gx) {
  const int d = blockIdx.z;
  const int g0 = blockIdx.x * 64;
  const int m0 = blockIdx.y * 128;
  const float* Wd = W + (size_t)d * GG * CC;

  __shared__ ushort Ah[128][64];
  __shared__ ushort Al[128][64];
  __shared__ ushort Bh[64][64];
  __shared__ ushort Bl[64][64];

  const int tid = threadIdx.x;
  const int lane = tid & 63;
  const int wid = tid >> 6;
  const int wm = (wid >> 1) * 64;
  const int wg = (wid & 1) * 32;

  f32x4v acc[4][2] = {};

  for (int k0 = 0; k0 < CC; k0 += 64) {
    __syncthreads();  // protect LDS from previous iteration's readers
    // stage A (pure 16B copies, swizzled LDS dest)
#pragma unroll
    for (int c = 0; c < 4; c++) {
      const int f8 = c * 256 + tid;          // ushort8 index, 0..1023
      const int r = f8 >> 3;                 // row 0..127
      const int kb = f8 & 7;                 // k-block (8 ushorts)
      const int sw = (kb ^ (r & 7)) << 3;
      const uint4 vh = *(const uint4*)&Ahi[(size_t)(m0 + r) * CC + k0 + kb * 8];
      const uint4 vl = *(const uint4*)&Alo[(size_t)(m0 + r) * CC + k0 + kb * 8];
      *(uint4*)&Ah[r][sw] = vh;
      *(uint4*)&Al[r][sw] = vl;
    }
    // stage B: fp32 -> bf16 hi/lo convert
#pragma unroll
    for (int c = 0; c < 4; c++) {
      const int f4 = c * 256 + tid;          // float4 index, 0..1023
      const int g = f4 >> 4;                 // 0..63
      const int k4 = f4 & 15;                // float4 within row
      const float4 wv = *(const float4*)&Wd[(size_t)(g0 + g) * CC + k0 + k4 * 4];
      ushort h0 = bf16_rn(wv.x), h1 = bf16_rn(wv.y), h2 = bf16_rn(wv.z), h3 = bf16_rn(wv.w);
      ushort l0 = bf16_rn(wv.x - bf16_to_f(h0)), l1 = bf16_rn(wv.y - bf16_to_f(h1));
      ushort l2 = bf16_rn(wv.z - bf16_to_f(h2)), l3 = bf16_rn(wv.w - bf16_to_f(h3));
      const int off = (((k4 >> 1) ^ (g & 7)) << 3) | ((k4 & 1) * 4);
      uint2 ph; ph.x = pack2(h0, h1); ph.y = pack2(h2, h3);
      uint2 pl; pl.x = pack2(l0, l1); pl.y = pack2(l2, l3);
      *(uint2*)&Bh[g][off] = ph;
      *(uint2*)&Bl[g][off] = pl;
    }
    __syncthreads();
#pragma unroll
    for (int h = 0; h < 2; h++) {
      const int kb = h * 4 + (lane >> 4);    // k-block 0..7 within BK
      bf16x8 afh[4], afl[4], bfh[2], bfl[2];
#pragma unroll
      for (int i = 0; i < 4; i++) {
        const int row = wm + i * 16 + (lane & 15);
        const int sw = (kb ^ (row & 7)) << 3;
        afh[i] = *(const bf16x8*)&Ah[row][sw];
        afl[i] = *(const bf16x8*)&Al[row][sw];
      }
#pragma unroll
      for (int j = 0; j < 2; j++) {
        const int gr = wg + j * 16 + (lane & 15);
        const int sw = (kb ^ (gr & 7)) << 3;
        bfh[j] = *(const bf16x8*)&Bh[gr][sw];
        bfl[j] = *(const bf16x8*)&Bl[gr][sw];
      }
#pragma unroll
      for (int i = 0; i < 4; i++)
#pragma unroll
        for (int j = 0; j < 2; j++) {
          acc[i][j] = __builtin_amdgcn_mfma_f32_16x16x32_bf16(afh[i], bfh[j], acc[i][j], 0, 0, 0);
          acc[i][j] = __builtin_amdgcn_mfma_f32_16x16x32_bf16(afh[i], bfl[j], acc[i][j], 0, 0, 0);
          acc[i][j] = __builtin_amdgcn_mfma_f32_16x16x32_bf16(afl[i], bfh[j], acc[i][j], 0, 0, 0);
        }
    }
  }
  // epilogue: bias + store (C/D: col=lane&15, row=(lane>>4)*4+reg — m89/m91 verified)
  const int col = lane & 15;
  const int rbase = (lane >> 4) * 4;
#pragma unroll
  for (int j = 0; j < 2; j++) {
    const int g = g0 + wg + j * 16 + col;
    const float bias = bih[d * GG + g] + bhh[d * GG + g];
#pragma unroll
    for (int i = 0; i < 4; i++) {
      const int mrow = m0 + wm + i * 16 + rbase;
#pragma unroll
      for (int rr = 0; rr < 4; rr++)
        gx[((size_t)d * MM + mrow + rr) * GG + g] = acc[i][j][rr] + bias;
    }
  }
}

// ---------------- persistent recurrence: one WG per (d,b) — R5 structure ----------------
// Thread (q=tid>>7, j=tid&127): 4 gates x 32-K quarter. Dot rewritten as plain-C f32x2
// vector math -> compiler may emit v_pk_fma_f32 (2 FMA/lane/cyc, halves the 512-cyc
// fp32 issue floor). No asm operand constraints (R6: forcing "v" off AGPR-resident
// weights added copies, +93us). Output mode: bf16 hi/lo (layer0 -> feeds MFMA gemm)
// or fp32 (layer1 -> transpose_out).
__global__ __launch_bounds__(512, 1) void k_lstm_rec(const float* __restrict__ gx,
                                                     const float* __restrict__ Whh,
                                                     float* __restrict__ hf32,
                                                     ushort* __restrict__ hhi,
                                                     ushort* __restrict__ hlo,
                                                     int store_bf16) {
  const int b = blockIdx.x & 31;
  const int d = blockIdx.x >> 5;
  const int tid = threadIdx.x;
  const int q = tid >> 7;       // K-quarter (wave-uniform)
  const int j = tid & 127;
  __shared__ __align__(16) float h_s[HH];
  __shared__ __align__(16) float part[4][HH][4];

  f32x2 w2[4][16];
  {
    const float* base = Whh + (size_t)d * GG * HH;
#pragma unroll
    for (int gi = 0; gi < 4; gi++) {
      const float4* wrow = (const float4*)(base + (size_t)(gi * HH + j) * HH + q * 32);
#pragma unroll
      for (int k = 0; k < 8; k++) {
        const float4 t4 = wrow[k];
        w2[gi][2 * k] = f32x2{t4.x, t4.y};
        w2[gi][2 * k + 1] = f32x2{t4.z, t4.w};
      }
    }
  }
#pragma unroll
  for (int gi = 0; gi < 4; gi++)
#pragma unroll
    for (int k = 0; k < 16; k++)
      asm volatile("" : "+v"(w2[gi][k]));

  if (tid < HH) h_s[tid] = 0.f;
  float c = 0.f;

  const float* gxb = gx + ((size_t)d * TT * BB + b) * (size_t)GG;
  const size_t stride = (size_t)BB * GG;
  int t = d ? (TT - 1) : 0;
  const int tdir = d ? -1 : 1;
  const bool is_act = (tid < HH);

  float gxc0 = 0.f, gxc1 = 0.f, gxc2 = 0.f, gxc3 = 0.f;
  if (is_act) {
    const float* g0 = gxb + (size_t)t * stride + j;
    gxc0 = g0[0]; gxc1 = g0[HH]; gxc2 = g0[2 * HH]; gxc3 = g0[3 * HH];
  }
  __syncthreads();

  for (int s = 0; s < TT; s++) {
    float gxn0 = 0.f, gxn1 = 0.f, gxn2 = 0.f, gxn3 = 0.f;
    if (is_act && s + 1 < TT) {
      const float* g0 = gxb + (size_t)(t + tdir) * stride + j;
      gxn0 = g0[0]; gxn1 = g0[HH]; gxn2 = g0[2 * HH]; gxn3 = g0[3 * HH];
    }

    // h K-slice: 8 uniform b128 reads, split to f32x2
    f32x2 hp[16];
    {
      const float4* hq = (const float4*)(h_s + q * 32);
#pragma unroll
      for (int k = 0; k < 8; k++) {
        const float4 hv = hq[k];
        hp[2 * k] = f32x2{hv.x, hv.y};
        hp[2 * k + 1] = f32x2{hv.z, hv.w};
      }
    }

    // dot: 4 gates x 32 K as packed f32x2 FMAs (8 independent chains)
    f32x2 aA0 = {0.f, 0.f}, aA1 = {0.f, 0.f}, aA2 = {0.f, 0.f}, aA3 = {0.f, 0.f};
    f32x2 aB0 = {0.f, 0.f}, aB1 = {0.f, 0.f}, aB2 = {0.f, 0.f}, aB3 = {0.f, 0.f};
#pragma unroll
    for (int k = 0; k < 8; k++) {
      aA0 = w2[0][2 * k] * hp[2 * k] + aA0;  aB0 = w2[0][2 * k + 1] * hp[2 * k + 1] + aB0;
      aA1 = w2[1][2 * k] * hp[2 * k] + aA1;  aB1 = w2[1][2 * k + 1] * hp[2 * k + 1] + aB1;
      aA2 = w2[2][2 * k] * hp[2 * k] + aA2;  aB2 = w2[2][2 * k + 1] * hp[2 * k + 1] + aB2;
      aA3 = w2[3][2 * k] * hp[2 * k] + aA3;  aB3 = w2[3][2 * k + 1] * hp[2 * k + 1] + aB3;
    }
    const float A0 = (aA0.x + aA0.y) + (aB0.x + aB0.y);
    const float A1 = (aA1.x + aA1.y) + (aB1.x + aB1.y);
    const float A2 = (aA2.x + aA2.y) + (aB2.x + aB2.y);
    const float A3 = (aA3.x + aA3.y) + (aB3.x + aB3.y);
    *(float4*)&part[q][j][0] = make_float4(A0, A1, A2, A3);
    __syncthreads();

    if (is_act) {
      const float4 p0 = *(const float4*)&part[0][j][0];
      const float4 p1 = *(const float4*)&part[1][j][0];
      const float4 p2 = *(const float4*)&part[2][j][0];
      const float4 p3 = *(const float4*)&part[3][j][0];
      const float i_g = fsig(p0.x + p1.x + p2.x + p3.x + gxc0);
      const float f_g = fsig(p0.y + p1.y + p2.y + p3.y + gxc1);
      const float g_g = ftanh(p0.z + p1.z + p2.z + p3.z + gxc2);
      const float o_g = fsig(p0.w + p1.w + p2.w + p3.w + gxc3);
      c = f_g * c + i_g * g_g;
      const float h = o_g * ftanh(c);
      h_s[j] = h;
      const size_t idx = ((size_t)t * BB + b) * CC + d * HH + j;
      if (store_bf16) {
        const ushort hi = bf16_rn(h);
        hhi[idx] = hi;
        hlo[idx] = bf16_rn(h - bf16_to_f(hi));
      } else {
        hf32[idx] = h;
      }
    }
    __syncthreads();
    gxc0 = gxn0; gxc1 = gxn1; gxc2 = gxn2; gxc3 = gxn3;
    t += tdir;
  }
}

extern "C" void kernel_launch(void* const* d_in, const int* in_sizes, int n_in,
                              void* d_out, int out_size, void* d_ws, size_t ws_size,
                              hipStream_t stream) {
  const float* x    = (const float*)d_in[0];
  const float* W_ih = (const float*)d_in[1];  // [2][2][512][256]
  const float* W_hh = (const float*)d_in[2];  // [2][2][512][128]
  const float* b_ih = (const float*)d_in[3];  // [2][2][512]
  const float* b_hh = (const float*)d_in[4];
  float* out = (float*)d_out;

  if (ws_size < (size_t)160 * 1024 * 1024) return;

  // A-region (32 MiB, ws+0) is recycled three times:
  //   Xhi/Xlo (transpose_cvt) -> h1hi/h1lo (rec0) -> h2 fp32 (rec1)
  char* ws = (char*)d_ws;
  ushort* abf_hi = (ushort*)ws;                              // 16 MiB
  ushort* abf_lo = (ushort*)(ws + (size_t)16 * 1024 * 1024); // 16 MiB
  float*  h2     = (float*)ws;                               // 32 MiB (rec1 output)
  float*  gxbuf  = (float*)(ws + (size_t)32 * 1024 * 1024);  // [D][M][512] 128 MiB

  const dim3 tb(32, 8);
  const dim3 tg(TT / 32, CC / 32, BB);
  const dim3 gemm_grid(GG / 64, MM / 128, 2);

  k_transpose_cvt_in<<<tg, tb, 0, stream>>>(x, abf_hi, abf_lo);
  k_gemm_mfma<<<gemm_grid, 256, 0, stream>>>(abf_hi, abf_lo, W_ih, b_ih, b_hh, gxbuf);
  k_lstm_rec<<<64, 512, 0, stream>>>(gxbuf, W_hh, nullptr, abf_hi, abf_lo, 1);
  k_gemm_mfma<<<gemm_grid, 256, 0, stream>>>(abf_hi, abf_lo, W_ih + 2 * GG * CC,
                                             b_ih + 2 * GG, b_hh + 2 * GG, gxbuf);
  k_lstm_rec<<<64, 512, 0, stream>>>(gxbuf, W_hh + 2 * GG * HH, h2, nullptr, nullptr, 0);
  k_transpose_out<<<tg, tb, 0, stream>>>(h2, out);
}